// Round 5
// baseline (185.211 us; speedup 1.0000x reference)
//
#include <hip/hip_runtime.h>
#include <hip/hip_cooperative_groups.h>

namespace cg = cooperative_groups;

#define N 2000
#define NCLS 21
#define MAXPC 50
#define MAXPI 100
#define IOU_THR 0.7f
#define NEGV -1000000000.0f
#define NBLK (NCLS * 32)

typedef unsigned long long u64;
typedef unsigned int u32;

// monotone float -> uint32 map (order-preserving, incl. negatives)
__device__ __forceinline__ u32 sortable(float s) {
    u32 u = __float_as_uint(s);
    return ((int)u < 0) ? ~u : (u | 0x80000000u);
}

// decode one box on the fly (bit-identical to reference formula)
__device__ __forceinline__ float4 decode_one(const float* __restrict__ rpn,
                                             const float* __restrict__ deltas, int i) {
    float4 p = ((const float4*)rpn)[i];
    float4 d = ((const float4*)deltas)[i];
    float h = p.z - p.x, w = p.w - p.y;
    float cy = p.x + 0.5f * h, cx = p.y + 0.5f * w;
    float pcy = d.x * h + cy;
    float pcx = d.y * w + cx;
    float ph = h * expf(d.z);
    float pw = w * expf(d.w);
    return make_float4(pcy - 0.5f * ph, pcx - 0.5f * pw, pcy + 0.5f * ph, pcx + 0.5f * pw);
}

__device__ __forceinline__ float iou_vs(float4 b, float ar,
                                        float kx, float ky, float kz, float kw) {
    float ka = (kz - kx) * (kw - ky);
    float iy1 = fmaxf(b.x, kx), ix1 = fmaxf(b.y, ky);
    float iy2 = fminf(b.z, kz), ix2 = fminf(b.w, kw);
    float inter = fmaxf(iy2 - iy1, 0.f) * fmaxf(ix2 - ix1, 0.f);
    return inter / fmaxf(ar + ka - inter, 1e-8f);
}

// One cooperative launch, three phases separated by grid.sync():
//  P1: per-class stable sort (rank counting), 672 blocks
//  P2: per-class greedy NMS, register-resident kept list, wave 0 of blocks 0..20
//  P3: per-class top-100 ranking via binary search, blocks 0..20
__global__ void __launch_bounds__(256, 4)
fused_kernel(const float* __restrict__ rpn, const float* __restrict__ deltas,
             const float* __restrict__ score,
             int* __restrict__ order, int* __restrict__ keep_pos,
             int* __restrict__ keep_cnt, u64* __restrict__ cand_key,
             float* __restrict__ out) {
    cg::grid_group grid = cg::this_grid();
    __shared__ __align__(16) u64 sk[N];       // P1: 2000 sort keys; P3: 21x50 cand keys
    __shared__ int scnt[NCLS];

    int bx = blockIdx.x;
    int tid = threadIdx.x;
    int c = bx >> 5;        // class
    int b = bx & 31;        // row-chunk within class

    // ---------- Phase 1: stable descending sort per class ----------
    for (int i = tid; i < N; i += 256) {
        u32 u = sortable(score[i * NCLS + c]);
        sk[i] = ((u64)u << 32) | (u32)(~i);
    }
    __syncthreads();
    {
        int i = b * 64 + (tid >> 2);
        int q = tid & 3;
        if (i < N) {
            u64 ki = sk[i];
            const ulonglong2* s2 = (const ulonglong2*)sk;
            int r = 0;
            int jj0 = q * 250;
#pragma unroll 4
            for (int jj = jj0; jj < jj0 + 250; jj++) {
                ulonglong2 v = s2[jj];
                r += (v.x > ki);
                r += (v.y > ki);
            }
            r += __shfl_xor(r, 1);
            r += __shfl_xor(r, 2);
            if (q == 0) order[c * N + r] = i;
        }
    }
    grid.sync();

    // ---------- Phase 2: greedy NMS, one wave per class ----------
    if (bx < NCLS && tid < 64) {
        int cc = bx;
        int lane = tid;
        float4 kb = make_float4(0.f, 0.f, 0.f, 0.f);   // kept box for slot 'lane'
        int nk = 0;
        const int NCH = (N + 63) / 64;
        for (int chunk = 0; chunk < NCH && nk < MAXPC; chunk++) {
            int pos = chunk * 64 + lane;
            bool valid = pos < N;
            int oi = valid ? order[cc * N + pos] : 0;
            float4 bb = decode_one(rpn, deltas, oi);
            float ar = (bb.z - bb.x) * (bb.w - bb.y);
            bool sup = !valid;
            for (int k = 0; k < nk; k++) {             // vs already-kept (shfl bcast)
                float kx = __shfl(kb.x, k), ky = __shfl(kb.y, k);
                float kz = __shfl(kb.z, k), kw = __shfl(kb.w, k);
                sup = sup || (iou_vs(bb, ar, kx, ky, kz, kw) > IOU_THR);
            }
            u64 alive = __ballot(!sup);
            while (alive && nk < MAXPC) {              // in-wave greedy resolve
                int l = __ffsll((unsigned long long)alive) - 1;
                float bxx = __shfl(bb.x, l), bxy = __shfl(bb.y, l);
                float bxz = __shfl(bb.z, l), bxw = __shfl(bb.w, l);
                if (lane == nk) kb = make_float4(bxx, bxy, bxz, bxw);
                if (lane == l) {
                    keep_pos[cc * MAXPC + nk] = pos;
                    u32 u = sortable(score[oi * NCLS + cc]);
                    cand_key[cc * MAXPC + nk] = ((u64)u << 32) | (u32)(~(cc * N + pos));
                }
                nk++;
                if (lane > l && !sup)
                    sup = (iou_vs(bb, ar, bxx, bxy, bxz, bxw) > IOU_THR);
                u64 nb = __ballot(!sup);
                alive = (l >= 63) ? 0ull : (nb & (~0ull << (l + 1)));
            }
        }
        if (lane == 0) keep_cnt[cc] = nk;
    }
    grid.sync();

    // ---------- Phase 3: global top-100 via per-class binary-search ranking ----
    if (bx < NCLS) {
        for (int t = tid; t < NCLS * MAXPC; t += 256)
            sk[t] = cand_key[t];
        if (tid < NCLS) scnt[tid] = keep_cnt[tid];
        __syncthreads();
        int M = 0;
#pragma unroll
        for (int c2 = 0; c2 < NCLS; c2++) M += scnt[c2];

        int cc = bx;
        if (tid < scnt[cc]) {
            u64 ki = sk[cc * MAXPC + tid];
            int r = tid;                         // rank within own descending list
#pragma unroll
            for (int c2 = 0; c2 < NCLS; c2++) {
                if (c2 == cc) continue;
                int lo = 0, hi = scnt[c2];
                while (lo < hi) {                // count of keys[c2][*] > ki
                    int mid = (lo + hi) >> 1;
                    if (sk[c2 * MAXPC + mid] > ki) lo = mid + 1; else hi = mid;
                }
                r += lo;
            }
            if (r < MAXPI) {
                int flat = (int)(~(u32)ki);
                int pos = flat - cc * N;
                int oi = order[cc * N + pos];
                float4 bb = decode_one(rpn, deltas, oi);
                out[r * 4 + 0] = bb.x;
                out[r * 4 + 1] = bb.y;
                out[r * 4 + 2] = bb.z;
                out[r * 4 + 3] = bb.w;
                out[4 * MAXPI + r] = (float)cc;
            }
        }
        // rare path: M<100 -> fill with NEG entries, smallest flat first (class 0
        // positions; among pos 0..149 at most 50 kept -> >=100 invalid slots).
        if (cc == 0 && tid == 0 && M < MAXPI) {
            int m = M;
            int cnt0 = scnt[0];
            for (int pos = 0; pos < 150 && m < MAXPI; pos++) {
                bool validp = false;
                for (int k = 0; k < cnt0; k++)
                    if (keep_pos[k] == pos) { validp = true; break; }
                if (!validp) {
                    int oi = order[pos];
                    float4 bb = decode_one(rpn, deltas, oi);
                    out[m * 4 + 0] = bb.x;
                    out[m * 4 + 1] = bb.y;
                    out[m * 4 + 2] = bb.z;
                    out[m * 4 + 3] = bb.w;
                    out[4 * MAXPI + m] = 0.0f;
                    m++;
                }
            }
        }
    }
}

extern "C" void kernel_launch(void* const* d_in, const int* in_sizes, int n_in,
                              void* d_out, int out_size, void* d_ws, size_t ws_size,
                              hipStream_t stream) {
    const float* rpn    = (const float*)d_in[0];  // [2000,4]
    const float* deltas = (const float*)d_in[1];  // [2000,4]
    const float* score  = (const float*)d_in[2];  // [2000,21]
    float* out = (float*)d_out;                   // 400 box floats + 100 cls

    char* ws = (char*)d_ws;
    int*   order    = (int*)(ws);                 // 168000 B
    u64*   candk    = (u64*)(ws + 168000);        // 8400 B (8-aligned)
    int*   keep_pos = (int*)(ws + 176400);        // 4200 B
    int*   keep_cnt = (int*)(ws + 180600);        // 84 B

    void* args[] = { (void*)&rpn, (void*)&deltas, (void*)&score, (void*)&order,
                     (void*)&keep_pos, (void*)&keep_cnt, (void*)&candk, (void*)&out };
    hipLaunchCooperativeKernel((const void*)fused_kernel, dim3(NBLK), dim3(256),
                               args, 0, stream);
}

// Round 6
// 112.779 us; speedup vs baseline: 1.6422x; 1.6422x over previous
//
#include <hip/hip_runtime.h>

#define N 2000
#define NCLS 21
#define MAXPC 50
#define MAXPI 100
#define IOU_THR 0.7f
#define NBLK (NCLS * 32)

typedef unsigned long long u64;
typedef unsigned int u32;

// monotone float -> uint32 map (order-preserving, incl. negatives)
__device__ __forceinline__ u32 sortable(float s) {
    u32 u = __float_as_uint(s);
    return ((int)u < 0) ? ~u : (u | 0x80000000u);
}

// decode one box on the fly (bit-identical to reference formula)
__device__ __forceinline__ float4 decode_one(const float* __restrict__ rpn,
                                             const float* __restrict__ deltas, int i) {
    float4 p = ((const float4*)rpn)[i];
    float4 d = ((const float4*)deltas)[i];
    float h = p.z - p.x, w = p.w - p.y;
    float cy = p.x + 0.5f * h, cx = p.y + 0.5f * w;
    float pcy = d.x * h + cy;
    float pcx = d.y * w + cx;
    float ph = h * expf(d.z);
    float pw = w * expf(d.w);
    return make_float4(pcy - 0.5f * ph, pcx - 0.5f * pw, pcy + 0.5f * ph, pcx + 0.5f * pw);
}

__device__ __forceinline__ float iou_vs(float4 b, float ar,
                                        float kx, float ky, float kz, float kw) {
    float ka = (kz - kx) * (kw - ky);
    float iy1 = fmaxf(b.x, kx), ix1 = fmaxf(b.y, ky);
    float iy2 = fminf(b.z, kz), ix2 = fminf(b.w, kw);
    float inter = fmaxf(iy2 - iy1, 0.f) * fmaxf(ix2 - ix1, 0.f);
    return inter / fmaxf(ar + ka - inter, 1e-8f);
}

// Single launch. DAG scheduling via "last arriving block runs the next stage":
//  P1: all 672 blocks: per-class stable sort (rank counting)
//  P2: 32nd-arriving block of class c runs NMS(c) on wave 0 (register kept-list)
//  P3: 21st class to finish NMS runs the full top-100 (256 threads)
// No spinning, no co-residency assumption, deterministic output.
__global__ void __launch_bounds__(256, 4)
fused_kernel(const float* __restrict__ rpn, const float* __restrict__ deltas,
             const float* __restrict__ score,
             int* __restrict__ order, int* __restrict__ keep_pos,
             int* __restrict__ keep_cnt, u64* __restrict__ cand_key,
             int* __restrict__ arrive,      // [NCLS] zeroed each call
             int* __restrict__ done,        // [1]    zeroed each call
             float* __restrict__ out) {
    __shared__ __align__(16) u64 sk[N];     // P1: 2000 sort keys; P3: 21x50 cand keys
    __shared__ int scnt[NCLS];
    __shared__ int s_flag;

    int bx = blockIdx.x;
    int tid = threadIdx.x;
    int c = bx >> 5;        // class
    int b = bx & 31;        // row-chunk within class

    // ---------- Phase 1: stable descending sort per class ----------
    for (int i = tid; i < N; i += 256) {
        u32 u = sortable(score[i * NCLS + c]);
        sk[i] = ((u64)u << 32) | (u32)(~i);
    }
    __syncthreads();
    {
        int i = b * 64 + (tid >> 2);
        int q = tid & 3;
        if (i < N) {
            u64 ki = sk[i];
            const ulonglong2* s2 = (const ulonglong2*)sk;
            int r = 0;
            int jj0 = q * 250;
#pragma unroll 4
            for (int jj = jj0; jj < jj0 + 250; jj++) {
                ulonglong2 v = s2[jj];
                r += (v.x > ki);
                r += (v.y > ki);
            }
            r += __shfl_xor(r, 1);
            r += __shfl_xor(r, 2);
            if (q == 0) order[c * N + r] = i;
        }
    }
    __syncthreads();                        // drains this block's global stores
    if (tid == 0) {
        __threadfence();                    // release: order[] visible device-wide
        int old = atomicAdd(&arrive[c], 1);
        s_flag = (old == 31);
    }
    __syncthreads();
    if (!s_flag) return;                    // not the last sort block of class c
    __threadfence();                        // acquire: see all 32 blocks' order[]

    // ---------- Phase 2: greedy NMS for class c, wave 0 only ----------
    if (tid < 64) {
        int lane = tid;
        float4 kb = make_float4(0.f, 0.f, 0.f, 0.f);   // kept box held in lane 'nk'
        int nk = 0;
        const int NCH = (N + 63) / 64;
        for (int chunk = 0; chunk < NCH && nk < MAXPC; chunk++) {
            int pos = chunk * 64 + lane;
            bool valid = pos < N;
            int oi = valid ? order[c * N + pos] : 0;
            float4 bb = decode_one(rpn, deltas, oi);
            float ar = (bb.z - bb.x) * (bb.w - bb.y);
            bool sup = !valid;
            for (int k = 0; k < nk; k++) {             // vs already-kept (shfl bcast)
                float kx = __shfl(kb.x, k), ky = __shfl(kb.y, k);
                float kz = __shfl(kb.z, k), kw = __shfl(kb.w, k);
                sup = sup || (iou_vs(bb, ar, kx, ky, kz, kw) > IOU_THR);
            }
            u64 alive = __ballot(!sup);
            while (alive && nk < MAXPC) {              // in-wave greedy resolve
                int l = __ffsll((unsigned long long)alive) - 1;
                float bxx = __shfl(bb.x, l), bxy = __shfl(bb.y, l);
                float bxz = __shfl(bb.z, l), bxw = __shfl(bb.w, l);
                if (lane == nk) kb = make_float4(bxx, bxy, bxz, bxw);
                if (lane == l) {
                    keep_pos[c * MAXPC + nk] = pos;
                    u32 u = sortable(score[oi * NCLS + c]);
                    cand_key[c * MAXPC + nk] = ((u64)u << 32) | (u32)(~(c * N + pos));
                }
                nk++;
                if (lane > l && !sup)
                    sup = (iou_vs(bb, ar, bxx, bxy, bxz, bxw) > IOU_THR);
                u64 nb = __ballot(!sup);
                alive = (l >= 63) ? 0ull : (nb & (~0ull << (l + 1)));
            }
        }
        if (lane == 0) keep_cnt[c] = nk;
    }
    __syncthreads();                        // waves 1..3 waited here; stores drained
    if (tid == 0) {
        __threadfence();                    // release: cand_key/keep_* visible
        int old = atomicAdd(done, 1);
        s_flag = (old == NCLS - 1);
    }
    __syncthreads();
    if (!s_flag) return;                    // not the last class
    __threadfence();                        // acquire: see all classes' NMS output

    // ---------- Phase 3: global top-100 via binary-search ranking ----------
    for (int t = tid; t < NCLS * MAXPC; t += 256)
        sk[t] = cand_key[t];
    if (tid < NCLS) scnt[tid] = keep_cnt[tid];
    __syncthreads();
    int M = 0;
#pragma unroll
    for (int c2 = 0; c2 < NCLS; c2++) M += scnt[c2];

    for (int t = tid; t < NCLS * MAXPC; t += 256) {
        int cc = t / MAXPC, k = t - cc * MAXPC;
        if (k >= scnt[cc]) continue;
        u64 ki = sk[t];
        int r = k;                           // rank within own descending list
#pragma unroll
        for (int c2 = 0; c2 < NCLS; c2++) {
            if (c2 == cc) continue;
            int lo = 0, hi = scnt[c2];
            while (lo < hi) {                // count of keys[c2][*] > ki
                int mid = (lo + hi) >> 1;
                if (sk[c2 * MAXPC + mid] > ki) lo = mid + 1; else hi = mid;
            }
            r += lo;
        }
        if (r < MAXPI) {
            int flat = (int)(~(u32)ki);
            int pos = flat - cc * N;
            int oi = order[cc * N + pos];
            float4 bb = decode_one(rpn, deltas, oi);
            out[r * 4 + 0] = bb.x;
            out[r * 4 + 1] = bb.y;
            out[r * 4 + 2] = bb.z;
            out[r * 4 + 3] = bb.w;
            out[4 * MAXPI + r] = (float)cc;
        }
    }
    // rare path: M<100 -> fill with NEG entries, smallest flat first (class 0
    // positions; among pos 0..149 at most 50 kept -> >=100 invalid slots).
    if (tid == 0 && M < MAXPI) {
        int m = M;
        int cnt0 = scnt[0];
        for (int pos = 0; pos < 150 && m < MAXPI; pos++) {
            bool validp = false;
            for (int k = 0; k < cnt0; k++)
                if (keep_pos[k] == pos) { validp = true; break; }
            if (!validp) {
                int oi = order[pos];
                float4 bb = decode_one(rpn, deltas, oi);
                out[m * 4 + 0] = bb.x;
                out[m * 4 + 1] = bb.y;
                out[m * 4 + 2] = bb.z;
                out[m * 4 + 3] = bb.w;
                out[4 * MAXPI + m] = 0.0f;
                m++;
            }
        }
    }
}

extern "C" void kernel_launch(void* const* d_in, const int* in_sizes, int n_in,
                              void* d_out, int out_size, void* d_ws, size_t ws_size,
                              hipStream_t stream) {
    const float* rpn    = (const float*)d_in[0];  // [2000,4]
    const float* deltas = (const float*)d_in[1];  // [2000,4]
    const float* score  = (const float*)d_in[2];  // [2000,21]
    float* out = (float*)d_out;                   // 400 box floats + 100 cls

    char* ws = (char*)d_ws;
    int*   order    = (int*)(ws);                 // 168000 B
    u64*   candk    = (u64*)(ws + 168000);        // 8400 B (8-aligned)
    int*   keep_pos = (int*)(ws + 176400);        // 4200 B
    int*   keep_cnt = (int*)(ws + 180600);        // 84 B
    int*   arrive   = (int*)(ws + 180736);        // 21 ints
    int*   done     = (int*)(ws + 180736 + 21 * 4); // 1 int

    // counters MUST be zeroed every call (d_ws is not re-poisoned between replays)
    hipMemsetAsync(arrive, 0, 128, stream);
    fused_kernel<<<NBLK, 256, 0, stream>>>(rpn, deltas, score, order,
                                           keep_pos, keep_cnt, candk,
                                           arrive, done, out);
}

// Round 7
// 104.131 us; speedup vs baseline: 1.7786x; 1.0831x over previous
//
#include <hip/hip_runtime.h>

#define N 2000
#define NCLS 21
#define MAXPC 50
#define MAXPI 100
#define IOU_THR 0.7f
#define NBLK (NCLS * 32)

typedef unsigned long long u64;
typedef unsigned int u32;

// monotone float -> uint32 map (order-preserving, incl. negatives)
__device__ __forceinline__ u32 sortable(float s) {
    u32 u = __float_as_uint(s);
    return ((int)u < 0) ? ~u : (u | 0x80000000u);
}

// decode one box on the fly (bit-identical to reference formula)
__device__ __forceinline__ float4 decode_one(const float* __restrict__ rpn,
                                             const float* __restrict__ deltas, int i) {
    float4 p = ((const float4*)rpn)[i];
    float4 d = ((const float4*)deltas)[i];
    float h = p.z - p.x, w = p.w - p.y;
    float cy = p.x + 0.5f * h, cx = p.y + 0.5f * w;
    float pcy = d.x * h + cy;
    float pcx = d.y * w + cx;
    float ph = h * expf(d.z);
    float pw = w * expf(d.w);
    return make_float4(pcy - 0.5f * ph, pcx - 0.5f * pw, pcy + 0.5f * ph, pcx + 0.5f * pw);
}

__device__ __forceinline__ float iou_vs(float4 b, float ar,
                                        float kx, float ky, float kz, float kw) {
    float ka = (kz - kx) * (kw - ky);
    float iy1 = fmaxf(b.x, kx), ix1 = fmaxf(b.y, ky);
    float iy2 = fminf(b.z, kz), ix2 = fminf(b.w, kw);
    float inter = fmaxf(iy2 - iy1, 0.f) * fmaxf(ix2 - ix1, 0.f);
    return inter / fmaxf(ar + ka - inter, 1e-8f);
}

// Single launch. DAG scheduling via "last arriving block runs the next stage".
// Synchronization: producers use RELEASE-scoped atomic add (L2 writeback only,
// NO invalidate); only the winning consumer block pays an ACQUIRE fence
// (invalidate). This avoids r6's 693 full __threadfence() L2 wb+inv storms.
__global__ void __launch_bounds__(256, 4)
fused_kernel(const float* __restrict__ rpn, const float* __restrict__ deltas,
             const float* __restrict__ score,
             int* __restrict__ order, int* __restrict__ keep_pos,
             int* __restrict__ keep_cnt, u64* __restrict__ cand_key,
             int* __restrict__ arrive,      // [NCLS] zeroed each call
             int* __restrict__ done,        // [1]    zeroed each call
             float* __restrict__ out) {
    __shared__ __align__(16) u64 sk[N];     // P1: 2000 sort keys; P3: 21x50 cand keys
    __shared__ int scnt[NCLS];
    __shared__ int s_flag;

    int bx = blockIdx.x;
    int tid = threadIdx.x;
    int c = bx >> 5;        // class
    int b = bx & 31;        // row-chunk within class

    // ---------- Phase 1: stable descending sort per class ----------
    for (int i = tid; i < N; i += 256) {
        u32 u = sortable(score[i * NCLS + c]);
        sk[i] = ((u64)u << 32) | (u32)(~i);
    }
    __syncthreads();
    {
        int i = b * 64 + (tid >> 2);
        int q = tid & 3;
        if (i < N) {
            u64 ki = sk[i];
            const ulonglong2* s2 = (const ulonglong2*)sk;
            int r = 0;
            int jj0 = q * 250;
#pragma unroll 4
            for (int jj = jj0; jj < jj0 + 250; jj++) {
                ulonglong2 v = s2[jj];
                r += (v.x > ki);
                r += (v.y > ki);
            }
            r += __shfl_xor(r, 1);
            r += __shfl_xor(r, 2);
            if (q == 0) order[c * N + r] = i;
        }
    }
    __syncthreads();                        // drains this block's global stores (vmcnt 0)
    if (tid == 0) {
        // release: prior stores written back to coherent point, then count bumped
        int old = __hip_atomic_fetch_add(&arrive[c], 1, __ATOMIC_RELEASE,
                                         __HIP_MEMORY_SCOPE_AGENT);
        s_flag = (old == 31);
    }
    __syncthreads();
    if (!s_flag) return;                    // not the last sort block of class c
    __builtin_amdgcn_fence(__ATOMIC_ACQUIRE, "agent");  // invalidate: see peers' order[]

    // ---------- Phase 2: greedy NMS for class c, wave 0 only ----------
    if (tid < 64) {
        int lane = tid;
        float4 kb = make_float4(0.f, 0.f, 0.f, 0.f);   // kept box held in lane 'nk'
        int nk = 0;
        const int NCH = (N + 63) / 64;
        for (int chunk = 0; chunk < NCH && nk < MAXPC; chunk++) {
            int pos = chunk * 64 + lane;
            bool valid = pos < N;
            int oi = valid ? order[c * N + pos] : 0;
            float4 bb = decode_one(rpn, deltas, oi);
            float ar = (bb.z - bb.x) * (bb.w - bb.y);
            bool sup = !valid;
            for (int k = 0; k < nk; k++) {             // vs already-kept (shfl bcast)
                float kx = __shfl(kb.x, k), ky = __shfl(kb.y, k);
                float kz = __shfl(kb.z, k), kw = __shfl(kb.w, k);
                sup = sup || (iou_vs(bb, ar, kx, ky, kz, kw) > IOU_THR);
            }
            u64 alive = __ballot(!sup);
            while (alive && nk < MAXPC) {              // in-wave greedy resolve
                int l = __ffsll((unsigned long long)alive) - 1;
                float bxx = __shfl(bb.x, l), bxy = __shfl(bb.y, l);
                float bxz = __shfl(bb.z, l), bxw = __shfl(bb.w, l);
                if (lane == nk) kb = make_float4(bxx, bxy, bxz, bxw);
                if (lane == l) {
                    keep_pos[c * MAXPC + nk] = pos;
                    u32 u = sortable(score[oi * NCLS + c]);
                    cand_key[c * MAXPC + nk] = ((u64)u << 32) | (u32)(~(c * N + pos));
                }
                nk++;
                if (lane > l && !sup)
                    sup = (iou_vs(bb, ar, bxx, bxy, bxz, bxw) > IOU_THR);
                u64 nb = __ballot(!sup);
                alive = (l >= 63) ? 0ull : (nb & (~0ull << (l + 1)));
            }
        }
        if (lane == 0) keep_cnt[c] = nk;
    }
    __syncthreads();                        // waves 1..3 waited here; stores drained
    if (tid == 0) {
        int old = __hip_atomic_fetch_add(done, 1, __ATOMIC_RELEASE,
                                         __HIP_MEMORY_SCOPE_AGENT);
        s_flag = (old == NCLS - 1);
    }
    __syncthreads();
    if (!s_flag) return;                    // not the last class
    __builtin_amdgcn_fence(__ATOMIC_ACQUIRE, "agent");  // see all classes' NMS output

    // ---------- Phase 3: global top-100 via binary-search ranking ----------
    for (int t = tid; t < NCLS * MAXPC; t += 256)
        sk[t] = cand_key[t];
    if (tid < NCLS) scnt[tid] = keep_cnt[tid];
    __syncthreads();
    int M = 0;
#pragma unroll
    for (int c2 = 0; c2 < NCLS; c2++) M += scnt[c2];

    for (int t = tid; t < NCLS * MAXPC; t += 256) {
        int cc = t / MAXPC, k = t - cc * MAXPC;
        if (k >= scnt[cc]) continue;
        u64 ki = sk[t];
        int r = k;                           // rank within own descending list
#pragma unroll
        for (int c2 = 0; c2 < NCLS; c2++) {
            if (c2 == cc) continue;
            int lo = 0, hi = scnt[c2];
            while (lo < hi) {                // count of keys[c2][*] > ki
                int mid = (lo + hi) >> 1;
                if (sk[c2 * MAXPC + mid] > ki) lo = mid + 1; else hi = mid;
            }
            r += lo;
        }
        if (r < MAXPI) {
            int flat = (int)(~(u32)ki);
            int pos = flat - cc * N;
            int oi = order[cc * N + pos];
            float4 bb = decode_one(rpn, deltas, oi);
            out[r * 4 + 0] = bb.x;
            out[r * 4 + 1] = bb.y;
            out[r * 4 + 2] = bb.z;
            out[r * 4 + 3] = bb.w;
            out[4 * MAXPI + r] = (float)cc;
        }
    }
    // rare path: M<100 -> fill with NEG entries, smallest flat first (class 0
    // positions; among pos 0..149 at most 50 kept -> >=100 invalid slots).
    if (tid == 0 && M < MAXPI) {
        int m = M;
        int cnt0 = scnt[0];
        for (int pos = 0; pos < 150 && m < MAXPI; pos++) {
            bool validp = false;
            for (int k = 0; k < cnt0; k++)
                if (keep_pos[k] == pos) { validp = true; break; }
            if (!validp) {
                int oi = order[pos];
                float4 bb = decode_one(rpn, deltas, oi);
                out[m * 4 + 0] = bb.x;
                out[m * 4 + 1] = bb.y;
                out[m * 4 + 2] = bb.z;
                out[m * 4 + 3] = bb.w;
                out[4 * MAXPI + m] = 0.0f;
                m++;
            }
        }
    }
}

extern "C" void kernel_launch(void* const* d_in, const int* in_sizes, int n_in,
                              void* d_out, int out_size, void* d_ws, size_t ws_size,
                              hipStream_t stream) {
    const float* rpn    = (const float*)d_in[0];  // [2000,4]
    const float* deltas = (const float*)d_in[1];  // [2000,4]
    const float* score  = (const float*)d_in[2];  // [2000,21]
    float* out = (float*)d_out;                   // 400 box floats + 100 cls

    char* ws = (char*)d_ws;
    int*   order    = (int*)(ws);                 // 168000 B
    u64*   candk    = (u64*)(ws + 168000);        // 8400 B (8-aligned)
    int*   keep_pos = (int*)(ws + 176400);        // 4200 B
    int*   keep_cnt = (int*)(ws + 180600);        // 84 B
    int*   arrive   = (int*)(ws + 180736);        // 21 ints
    int*   done     = (int*)(ws + 180736 + 21 * 4); // 1 int

    // counters MUST be zeroed every call (d_ws is not re-poisoned between replays)
    hipMemsetAsync(arrive, 0, 128, stream);
    fused_kernel<<<NBLK, 256, 0, stream>>>(rpn, deltas, score, order,
                                           keep_pos, keep_cnt, candk,
                                           arrive, done, out);
}